// Round 7
// baseline (489.569 us; speedup 1.0000x reference)
//
#include <hip/hip_runtime.h>

#define Bsz 1024
#define Tt  256
#define Vv  32004
#define Dd  50
#define Hh  64
#define RR  32   // vocab rows per build_tables block

typedef __bf16 b16x8 __attribute__((ext_vector_type(8)));
typedef float  f32x4 __attribute__((ext_vector_type(4)));

// barrier WITHOUT vmcnt(0) drain: LDS ordering only, in-flight global loads
// (the xw register prefetch) survive across it.
__device__ __forceinline__ void barrier_novm() {
    asm volatile("s_waitcnt lgkmcnt(0)\n\ts_barrier" ::: "memory");
}
__device__ __forceinline__ void lds_fence() {
    asm volatile("s_waitcnt lgkmcnt(0)" ::: "memory");
}
__device__ __forceinline__ float fsig(float x) {
    return __fdividef(1.0f, 1.0f + __expf(-x));
}
__device__ __forceinline__ float ftanh(float x) {
    return 2.0f * __fdividef(1.0f, 1.0f + __expf(-2.0f * x)) - 1.0f;
}

// ---------------------------------------------------------------------------
// Prologue: tab[v][g] = sum_d emb[v][d] * Wih[g][d] + bih[g] + bhh[g]
// v3: only the weights live in LDS (wpack[13][256] float4, one b128/j).
// emb is read straight from global with WAVE-UNIFORM addresses -> scalar /
// broadcast loads; kills the 416 ds_read_b128/thread of v2.
// ---------------------------------------------------------------------------
__launch_bounds__(256, 2)
__global__ void build_tables(const float* __restrict__ emb,
                             const float* __restrict__ Wih1,
                             const float* __restrict__ bih1,
                             const float* __restrict__ bhh1,
                             const float* __restrict__ Wih2,
                             const float* __restrict__ bih2,
                             const float* __restrict__ bhh2,
                             float* __restrict__ tab1,
                             float* __restrict__ tab2) {
    const int v0 = blockIdx.x * RR;
    const int g  = threadIdx.x;
    const int nr = min(RR, Vv - v0);

    const float* Wih = blockIdx.y ? Wih2 : Wih1;
    const float* bih = blockIdx.y ? bih2 : bih1;
    const float* bhh = blockIdx.y ? bhh2 : bhh1;
    float*       tab = blockIdx.y ? tab2 : tab1;

    __shared__ __align__(16) float4 wpack[13 * 256];   // [j][g], 53.2 KB

    {
        const float* wrow = Wih + (size_t)g * Dd;
#pragma unroll
        for (int j = 0; j < 12; ++j) {
            const float2 a = *(const float2*)(wrow + 4 * j);
            const float2 b = *(const float2*)(wrow + 4 * j + 2);
            wpack[j * 256 + g] = make_float4(a.x, a.y, b.x, b.y);
        }
        const float2 t = *(const float2*)(wrow + 48);
        wpack[12 * 256 + g] = make_float4(t.x, t.y, 0.0f, 0.0f);
    }
    __syncthreads();

    const float bias = bih[g] + bhh[g];

    for (int cc = 0; cc < RR / 8; ++cc) {
        const int r0 = cc * 8;
        float acc[8];
#pragma unroll
        for (int r = 0; r < 8; ++r) acc[r] = 0.0f;

#pragma unroll
        for (int j = 0; j < 13; ++j) {
            const float4 wv = wpack[j * 256 + g];      // ds_read_b128, contiguous
#pragma unroll
            for (int r = 0; r < 8; ++r) {
                // clamp so tail block never reads past emb's last row
                const int rv = min(v0 + r0 + r, Vv - 1);
                const float* ep = emb + (size_t)rv * Dd + 4 * j;  // wave-uniform
                if (j < 12) {
                    const float2 e0 = *(const float2*)ep;
                    const float2 e1 = *(const float2*)(ep + 2);
                    acc[r] += e0.x * wv.x + e0.y * wv.y + e1.x * wv.z + e1.y * wv.w;
                } else {
                    const float2 e0 = *(const float2*)ep;      // cols 48,49
                    acc[r] += e0.x * wv.x + e0.y * wv.y;
                }
            }
        }

#pragma unroll
        for (int r = 0; r < 8; ++r) {
            if (r0 + r < nr)
                tab[(size_t)(v0 + r0 + r) * 256 + g] = acc[r] + bias;
        }
    }
}

// ---------------------------------------------------------------------------
// MFMA recurrence v2: 512 blocks x 2 batch rows x 256 threads (4 waves).
// 2 blocks/CU -> two independent barrier domains interleave (latency hiding).
// ONE barrier per step:
//   - hsh (h, bf16) double-buffered on step parity  -> no WAR barrier
//   - wave w computes the i/f/g/o gate tiles for hidden units [16w,16w+16),
//     so the C->update exchange is wave-private (lgkmcnt fence, no s_barrier)
// Update owners: lanes<32 of each wave, lane = row*16 + hid_local.
// ---------------------------------------------------------------------------
__launch_bounds__(256, 2)
__global__ void lstm_main(const int*   __restrict__ s1,
                          const int*   __restrict__ s2,
                          const int*   __restrict__ len1,
                          const int*   __restrict__ len2,
                          const float* __restrict__ tab1,
                          const float* __restrict__ tab2,
                          const float* __restrict__ Whh1,
                          const float* __restrict__ Whh2,
                          const float* __restrict__ Wl1,
                          const float* __restrict__ bl1,
                          const float* __restrict__ Wl2,
                          const float* __restrict__ bl2,
                          float* __restrict__ out) {
    const int tid  = threadIdx.x;
    const int wv   = tid >> 6;          // wave id -> hid group [16wv, 16wv+16)
    const int lane = tid & 63;
    const int q    = lane >> 4;         // MFMA quad
    const int mn   = lane & 15;         // MFMA m (A) / n (B,C) index
    const int b0   = blockIdx.x * 2;    // 2 batch rows per block

    const bool owner = lane < 32;       // update owners
    const int  un  = (lane >> 4) & 1;   // owner's batch row (0/1)
    const int  uj  = mn;                // owner's hid local (0..15)
    const int  hid = 16 * wv + uj;      // owner's global hidden unit

    __shared__ __bf16 hsh[2][16][72];      // [parity][n][k] (rows 2..15 unused)
    __shared__ float  gexch[4][2][4][16];  // [wave][row][gate][hidlocal]
    __shared__ int    toklds[2][Tt];
    __shared__ float  h2s[2][64];
    __shared__ float  ys[2][128];

    float c = 0.0f, hval = 0.0f, selh = 0.0f, selc = 0.0f;
    const f32x4 zero4 = {0.0f, 0.0f, 0.0f, 0.0f};

    for (int phase = 0; phase < 2; ++phase) {
        const float* tab  = phase ? tab2 : tab1;
        const float* Whh  = phase ? Whh2 : Whh1;
        const int*   sent = phase ? s2 : s1;
        const int*   lenp = phase ? len2 : len1;

        // stage this block's tokens (2 x 256, coalesced)
        for (int i = tid; i < 2 * Tt; i += 256) {
            const int r = i >> 8, t = i & (Tt - 1);
            toklds[r][t] = sent[(size_t)(b0 + r) * Tt + t];
        }

        // A-frags: wave wv owns gate tiles {64g + 16wv .. +16} for g=0..3
        // A[m = lane&15][k = quad*8 + j]; fp32 -> bf16 once per phase.
        b16x8 af[4][2];
#pragma unroll
        for (int g = 0; g < 4; ++g) {
            const int gate = 64 * g + 16 * wv + mn;
#pragma unroll
            for (int kh = 0; kh < 2; ++kh) {
                const float* ar = Whh + (size_t)gate * Hh + kh * 32 + q * 8;
                const float4 f0 = *(const float4*)ar;
                const float4 f1 = *(const float4*)(ar + 4);
                b16x8 a;
                a[0] = (__bf16)f0.x; a[1] = (__bf16)f0.y;
                a[2] = (__bf16)f0.z; a[3] = (__bf16)f0.w;
                a[4] = (__bf16)f1.x; a[5] = (__bf16)f1.y;
                a[6] = (__bf16)f1.z; a[7] = (__bf16)f1.w;
                af[g][kh] = a;
            }
        }

        const int myidx = owner ? lenp[(size_t)(b0 + un) * Hh + hid] : -2;

        if (phase) { c = selc; hval = selh; }       // gathered state seeds LSTM2
        if (owner) hsh[0][un][hid] = (__bf16)hval;  // t=0 reads parity 0
        selh = 0.0f; selc = 0.0f;
        __syncthreads();

        // xw register prefetch, distance 2
        const float* tabj = tab + hid;
        f32x4 Sa = zero4, Sb = zero4;
        if (owner) {
            const int tk0 = toklds[un][0];
            Sa[0] = tabj[tk0 * 256];       Sa[1] = tabj[tk0 * 256 + 64];
            Sa[2] = tabj[tk0 * 256 + 128]; Sa[3] = tabj[tk0 * 256 + 192];
            const int tk1 = toklds[un][1];
            Sb[0] = tabj[tk1 * 256];       Sb[1] = tabj[tk1 * 256 + 64];
            Sb[2] = tabj[tk1 * 256 + 128]; Sb[3] = tabj[tk1 * 256 + 192];
        }

        auto step = [&](int t, f32x4& S) {
            const int p = t & 1;
            // B frags: B[k = quad*8+j][n = lane&15] from hsh[p][n][k]
            const b16x8 bf0 = *(const b16x8*)&hsh[p][mn][q * 8];
            const b16x8 bf1 = *(const b16x8*)&hsh[p][mn][32 + q * 8];

            f32x4 ac0 = __builtin_amdgcn_mfma_f32_16x16x32_bf16(af[0][0], bf0, zero4, 0, 0, 0);
            ac0       = __builtin_amdgcn_mfma_f32_16x16x32_bf16(af[0][1], bf1, ac0,   0, 0, 0);
            f32x4 ac1 = __builtin_amdgcn_mfma_f32_16x16x32_bf16(af[1][0], bf0, zero4, 0, 0, 0);
            ac1       = __builtin_amdgcn_mfma_f32_16x16x32_bf16(af[1][1], bf1, ac1,   0, 0, 0);
            f32x4 ac2 = __builtin_amdgcn_mfma_f32_16x16x32_bf16(af[2][0], bf0, zero4, 0, 0, 0);
            ac2       = __builtin_amdgcn_mfma_f32_16x16x32_bf16(af[2][1], bf1, ac2,   0, 0, 0);
            f32x4 ac3 = __builtin_amdgcn_mfma_f32_16x16x32_bf16(af[3][0], bf0, zero4, 0, 0, 0);
            ac3       = __builtin_amdgcn_mfma_f32_16x16x32_bf16(af[3][1], bf1, ac3,   0, 0, 0);

            // C: row m = 4q+reg (hid local), col n = mn (batch row); n<2 valid
            if (mn < 2) {
                *(f32x4*)&gexch[wv][mn][0][4 * q] = ac0;
                *(f32x4*)&gexch[wv][mn][1][4 * q] = ac1;
                *(f32x4*)&gexch[wv][mn][2][4 * q] = ac2;
                *(f32x4*)&gexch[wv][mn][3][4 * q] = ac3;
            }
            lds_fence();   // wave-private exchange: no s_barrier needed

            if (owner) {
                const float gI = gexch[wv][un][0][uj] + S[0];
                const float gF = gexch[wv][un][1][uj] + S[1];
                const float gG = gexch[wv][un][2][uj] + S[2];
                const float gO = gexch[wv][un][3][uj] + S[3];
                // refill S for t+2
                const int tk = toklds[un][(t + 2 < Tt) ? t + 2 : Tt - 1];
                S[0] = tabj[tk * 256];       S[1] = tabj[tk * 256 + 64];
                S[2] = tabj[tk * 256 + 128]; S[3] = tabj[tk * 256 + 192];

                const float iv = fsig(gI);
                const float fv = fsig(gF);
                const float gv = ftanh(gG);
                const float ov = fsig(gO);
                c = fv * c + iv * gv;
                hval = ov * ftanh(c);
                if (t == myidx) { selh = hval; selc = c; }
                hsh[p ^ 1][un][hid] = (__bf16)hval;
            }
            barrier_novm();   // the ONE barrier: publish h for step t+1
        };

        for (int t = 0; t < Tt; t += 2) {
            step(t,     Sa);
            step(t + 1, Sb);
        }
    }

    // ---------------- epilogue MLP on the 2 gathered rows -------------------
    if (owner) h2s[un][hid] = selh;
    __syncthreads();
    {
        const int rr = tid >> 7, nn = tid & 127;   // 256 tasks = 2 rows x 128
        float a = bl1[nn];
        const float* wl = Wl1 + nn * 64;
#pragma unroll 8
        for (int k = 0; k < 64; ++k) a += h2s[rr][k] * wl[k];
        ys[rr][nn] = ftanh(a);
    }
    __syncthreads();
    if (tid < 8) {
        const int rr = tid >> 2, o = tid & 3;
        float a = bl2[o];
        const float* wl = Wl2 + o * 128;
#pragma unroll 8
        for (int k = 0; k < 128; ++k) a += ys[rr][k] * wl[k];
        out[(size_t)(b0 + rr) * 4 + o] = a;
    }
}

// ---------------------------------------------------------------------------
extern "C" void kernel_launch(void* const* d_in, const int* in_sizes, int n_in,
                              void* d_out, int out_size, void* d_ws, size_t ws_size,
                              hipStream_t stream) {
    const int*   s1   = (const int*)d_in[0];
    const int*   s2   = (const int*)d_in[1];
    const int*   l1   = (const int*)d_in[2];
    const int*   l2   = (const int*)d_in[3];
    // d_in[4], d_in[5] (s1_s, s2_s) unused by the reference
    const float* emb  = (const float*)d_in[6];
    const float* Wih1 = (const float*)d_in[7];
    const float* Whh1 = (const float*)d_in[8];
    const float* bih1 = (const float*)d_in[9];
    const float* bhh1 = (const float*)d_in[10];
    const float* Wih2 = (const float*)d_in[11];
    const float* Whh2 = (const float*)d_in[12];
    const float* bih2 = (const float*)d_in[13];
    const float* bhh2 = (const float*)d_in[14];
    const float* Wl1  = (const float*)d_in[15];
    const float* bl1  = (const float*)d_in[16];
    const float* Wl2  = (const float*)d_in[17];
    const float* bl2  = (const float*)d_in[18];
    float* out = (float*)d_out;

    float* tab1 = (float*)d_ws;                       // [V,256] fp32
    float* tab2 = tab1 + (size_t)Vv * 256;            // [V,256] fp32  (65.6 MB)

    dim3 grid((Vv + RR - 1) / RR, 2);
    build_tables<<<grid, 256, 0, stream>>>(emb, Wih1, bih1, bhh1,
                                           Wih2, bih2, bhh2, tab1, tab2);
    lstm_main<<<Bsz / 2, 256, 0, stream>>>(s1, s2, l1, l2, tab1, tab2,
                                           Whh1, Whh2, Wl1, bl1, Wl2, bl2, out);
}